// Round 5
// baseline (16807.260 us; speedup 1.0000x reference)
//
#include <hip/hip_runtime.h>
#include <stdint.h>

// Problem constants
#define Bv 16
#define Sv 2048
#define Iv 128
#define Hv 512
#define Ov 128

typedef __bf16 v8bf __attribute__((ext_vector_type(8)));
typedef float v4f __attribute__((ext_vector_type(4)));
#define MFMA(a, b, c) __builtin_amdgcn_mfma_f32_16x16x32_bf16((a), (b), (c), 0, 0, 0)

__device__ __forceinline__ float sigf(float x) { return 1.0f / (1.0f + __expf(-x)); }
__device__ __forceinline__ float tanh_fast(float x) { return 2.0f / (1.0f + __expf(-2.0f * x)) - 1.0f; }

__device__ __forceinline__ unsigned f2bf(float f) {
  union { __bf16 h; unsigned short u; } c; c.h = (__bf16)f; return (unsigned)c.u;
}
__device__ __forceinline__ float bf2f(unsigned short u) {
  union { __bf16 h; unsigned short u; } c; c.u = u; return (float)c.h;
}

__device__ __forceinline__ v8bf cvt8(const float* p) {
  v8bf r;
#pragma unroll
  for (int i = 0; i < 8; i++) r[i] = (__bf16)p[i];
  return r;
}

// relaxed agent-scope atomics (bypass non-coherent per-XCD L2).
// Coherence point = Infinity Cache.
__device__ __forceinline__ uint64_t ld64(const uint64_t* p) {
  return __hip_atomic_load((uint64_t*)p, __ATOMIC_RELAXED, __HIP_MEMORY_SCOPE_AGENT);
}
__device__ __forceinline__ void st32(unsigned* p, unsigned v) {
  __hip_atomic_store(p, v, __ATOMIC_RELAXED, __HIP_MEMORY_SCOPE_AGENT);
}
__device__ __forceinline__ unsigned ld32(const unsigned* p) {
  return __hip_atomic_load((unsigned*)p, __ATOMIC_RELAXED, __HIP_MEMORY_SCOPE_AGENT);
}

// Tagged payload, BLOCK-MAJOR: slot = 8192 u32 (32KB). Block wg's chunk =
// 256 u32 (1KB) at wg*256; word [rb*16+rj] = bf16(value) | tag<<16.
// Producer store: 1 u32/thread, fully coalesced (1KB contiguous per block).
__device__ __forceinline__ void store_val(unsigned* dslot, int wg, int tid, float val, unsigned tag) {
  st32(dslot + wg * 256 + tid, f2bf(val) | (tag << 16));
}

// Issue-order barrier only (no vmcnt drain): all threads have ISSUED their
// payload stores before lane0 posts the sentinel hint. Visibility ordering
// is NOT required -- consumers verify per-word tags.
__device__ __forceinline__ void post(unsigned* s, int idx, unsigned tag, int tid) {
  __builtin_amdgcn_s_barrier();
  if (tid == 0) st32(s + idx, tag);
}

// Poll 32 sentinel words (one 128B line) until all == want (hint only).
__device__ __forceinline__ void poll1(const unsigned* s, unsigned want, int tid) {
  unsigned r = 0;
  for (;;) {
    unsigned v = ld32(s + (tid & 31));
    if (__all(v == want) || ++r > (1u << 20)) break;  // valve: wrong beats hang
  }
}
__device__ __forceinline__ void poll2(const unsigned* sA, unsigned wA,
                                      const unsigned* sB, unsigned wB, int tid) {
  unsigned r = 0;
  for (;;) {
    unsigned a = ld32(sA + (tid & 31));
    unsigned b = ld32(sB + (tid & 31));
    if (__all((a == wA) && (b == wB)) || ++r > (1u << 20)) break;
  }
}

// Direct coalesced MFMA A-fragment read with tag verification.
// Lane (lm,lq) of `wave`, kb-th fragment: rows lm, cols k..k+7,
// k = wave*128+kb*32+lq*8. Chunk c=k>>4 -> u64 base =
// wave*1024 + kb*256 + (lq>>1)*128 + lm*8 + (lq&1)*4; 4 consecutive u64.
// Per wave-instruction the access covers 2KB contiguous (coalesced).
// Retry until every word carries `tag` (valve-capped).
__device__ __forceinline__ void ldfrags_tag(const unsigned* slot, int wave, int lm, int lq,
                                            unsigned tag, v8bf* a) {
  const uint64_t* base = (const uint64_t*)slot + wave * 1024 + (lq >> 1) * 128 + lm * 8 + (lq & 1) * 4;
  const uint64_t want = ((uint64_t)tag << 16) | ((uint64_t)tag << 48);
  const uint64_t MSK = 0xffff0000ffff0000ull;
  uint64_t W[16];
  unsigned r = 0;
  for (;;) {
    bool ok = true;
#pragma unroll
    for (int kb = 0; kb < 4; kb++)
#pragma unroll
      for (int j = 0; j < 4; j++) {
        uint64_t w = ld64(base + kb * 256 + j);
        W[kb * 4 + j] = w;
        ok &= ((w & MSK) == want);
      }
    if (__all(ok) || ++r > (1u << 18)) break;
    __builtin_amdgcn_s_sleep(1);
  }
#pragma unroll
  for (int kb = 0; kb < 4; kb++) {
    union { v8bf v; unsigned short s[8]; } u;
#pragma unroll
    for (int j = 0; j < 4; j++) {
      uint64_t w = W[kb * 4 + j];
      u.s[j * 2] = (unsigned short)(w & 0xffffu);
      u.s[j * 2 + 1] = (unsigned short)((w >> 32) & 0xffffu);
    }
    a[kb] = u.v;
  }
}
// Per-thread own-h value (chunk wg, word tid), tag-verified.
__device__ __forceinline__ float ldhval_tag(const unsigned* slot, int wg, int tid, unsigned tag) {
  unsigned r = 0, w;
  for (;;) {
    w = ld32(slot + wg * 256 + tid);
    if ((w >> 16) == tag || ++r > (1u << 18)) break;
    __builtin_amdgcn_s_sleep(1);
  }
  return bf2f((unsigned short)(w & 0xffffu));
}

__global__ __launch_bounds__(256, 1) void gru_fused(
    const float* __restrict__ x, const float* __restrict__ hs,
    const float* __restrict__ Wxz0, const float* __restrict__ Whz0, const float* __restrict__ bhz0,
    const float* __restrict__ Wxr0, const float* __restrict__ Whr0, const float* __restrict__ bhr0,
    const float* __restrict__ Wxz1, const float* __restrict__ Whz1, const float* __restrict__ bhz1,
    const float* __restrict__ Wxr1, const float* __restrict__ Whr1, const float* __restrict__ bhr1,
    const float* __restrict__ Why, const float* __restrict__ by,
    float* __restrict__ out, char* __restrict__ ws, int D) {
  const int tid = threadIdx.x;
  const int wave = tid >> 6;
  const int lane = tid & 63;
  const int lm = lane & 15;
  const int lq = lane >> 4;
  const int rb = tid >> 4;
  const int rj = tid & 15;
  const int m0 = D - 1;

  unsigned* prog = (unsigned*)ws;  // [32], zeroed by memset
  unsigned* h0s = (unsigned*)(ws + 1024);  // [D][32] sentinels
  unsigned* h1s = h0s + D * 32;            // [4][32]
  unsigned* u0s = h1s + 128;               // [2][32]
  unsigned* u1s = u0s + 64;                // [2][32]
  unsigned* h0d = (unsigned*)(ws + 16384); // [D][8192] tagged payload (32KB/slot)
  unsigned* h1d = h0d + (size_t)D * 8192;  // [4][8192]
  unsigned* u0d = h1d + 4 * 8192;          // [2][8192]
  unsigned* u1d = u0d + 2 * 8192;          // [2][8192]

  __shared__ float red[5][4][16][17];  // planes: 0=z 1=xr 2=hr 3=out 4=g

  const bool L0 = (blockIdx.x < 32);
  const int wg = L0 ? blockIdx.x : (blockIdx.x - 32);
  const int j0 = wg << 4;
  const bool OW = (!L0) && (wg < 8);
  const int jrow = j0 + lm;

  // ---- initial hidden state -> payload slot 0 (tag 1), sentinel hint 1 ----
  {
    float h0v = hs[((size_t)rb * 2 + (L0 ? 0 : 1)) * Hv + j0 + rj];
    store_val(L0 ? h0d : h1d, wg, tid, h0v, 1u);
    post(L0 ? h0s : h1s, wg, 1u, tid);
  }

  if (L0) {
    v8bf wzx0 = cvt8(Wxz0 + (size_t)jrow * Iv + wave * 32 + lq * 8);
    v8bf wrx0 = cvt8(Wxr0 + (size_t)jrow * Iv + wave * 32 + lq * 8);
    v8bf wzh[4], wrh[4];
#pragma unroll
    for (int kb = 0; kb < 4; kb++) {
      int k = wave * 128 + kb * 32 + lq * 8;
      wzh[kb] = cvt8(Whz0 + (size_t)jrow * Hv + k);
      wrh[kb] = cvt8(Whr0 + (size_t)jrow * Hv + k);
    }
    float bz = bhz0[j0 + rj], br = bhr0[j0 + rj];

    const int xk = wave * 32 + lq * 8;
    float4 xp0 = *(const float4*)(x + ((size_t)lm * Sv + 0) * Iv + xk);
    float4 xp1 = *(const float4*)(x + ((size_t)lm * Sv + 0) * Iv + xk + 4);

    for (int t = 0; t < Sv; ++t) {
      if (t >= D - 1 && tid < 32) {  // backpressure vs L1's y0 consumption
        unsigned need = (unsigned)(t - D + 2), it = 0;
        while (ld32(prog + tid) < need)
          if (++it > (1u << 20)) break;
      }
      poll1(h0s + (t & m0) * 32, (unsigned)(t + 1), tid);
      const unsigned* hslot = h0d + (size_t)(t & m0) * 8192;
      float hval = ldhval_tag(hslot, wg, tid, (unsigned)(t + 1));
      v8bf ah[4];
      ldfrags_tag(hslot, wave, lm, lq, (unsigned)(t + 1), ah);
      v8bf ax;
      {
        float xf[8] = {xp0.x, xp0.y, xp0.z, xp0.w, xp1.x, xp1.y, xp1.z, xp1.w};
#pragma unroll
        for (int i = 0; i < 8; i++) ax[i] = (__bf16)xf[i];
      }
      v4f az = {0, 0, 0, 0}, axr = {0, 0, 0, 0}, ahr = {0, 0, 0, 0};
      az = MFMA(ax, wzx0, az);
      axr = MFMA(ax, wrx0, axr);
#pragma unroll
      for (int kb = 0; kb < 4; kb++) {
        az = MFMA(ah[kb], wzh[kb], az);
        ahr = MFMA(ah[kb], wrh[kb], ahr);
      }
#pragma unroll
      for (int v = 0; v < 4; v++) {
        red[0][wave][lq * 4 + v][lm] = az[v];
        red[1][wave][lq * 4 + v][lm] = axr[v];
        red[2][wave][lq * 4 + v][lm] = ahr[v];
      }
      __syncthreads();
      float zs = 0, xrs = 0, hrs = 0;
#pragma unroll
      for (int w = 0; w < 4; w++) {
        zs += red[0][w][rb][rj];
        xrs += red[1][w][rb][rj];
        hrs += red[2][w][rb][rj];
      }
      float z = sigf(zs + bz);
      float r = sigf(xrs + hrs + br);
      store_val(u0d + (size_t)(t & 1) * 8192, wg, tid, r * hval, (unsigned)(t + 1));
      post(u0s + (t & 1) * 32, wg, (unsigned)(t + 1), tid);
      if (t + 1 < Sv) {  // prefetch next x (overlaps the u-hop)
        xp0 = *(const float4*)(x + ((size_t)lm * Sv + (t + 1)) * Iv + xk);
        xp1 = *(const float4*)(x + ((size_t)lm * Sv + (t + 1)) * Iv + xk + 4);
      }
      poll1(u0s + (t & 1) * 32, (unsigned)(t + 1), tid);
      v8bf au[4];
      ldfrags_tag(u0d + (size_t)(t & 1) * 8192, wave, lm, lq, (unsigned)(t + 1), au);
      v4f ag = {0, 0, 0, 0};
#pragma unroll
      for (int kb = 0; kb < 4; kb++) ag = MFMA(au[kb], wrh[kb], ag);
#pragma unroll
      for (int v = 0; v < 4; v++) red[4][wave][lq * 4 + v][lm] = ag[v];
      __syncthreads();
      float gs = 0;
#pragma unroll
      for (int w = 0; w < 4; w++) gs += red[4][w][rb][rj];
      float g = tanh_fast(xrs + gs + br);  // faithful to source bug
      float hn = z * hval + (1.f - z) * g;
      store_val(h0d + (size_t)((t + 1) & m0) * 8192, wg, tid, hn, (unsigned)(t + 2));
      if (t == Sv - 1) out[(size_t)Bv * Sv * Ov + ((size_t)rb * 2 + 0) * Hv + j0 + rj] = hn;
      post(h0s + ((t + 1) & m0) * 32, wg, (unsigned)(t + 2), tid);
    }
  } else {
    v8bf wzx1[4], wrx1[4], wzh[4], wrh[4], wo[4];
#pragma unroll
    for (int kb = 0; kb < 4; kb++) {
      int k = wave * 128 + kb * 32 + lq * 8;
      wzx1[kb] = cvt8(Wxz1 + (size_t)jrow * Hv + k);
      wrx1[kb] = cvt8(Wxr1 + (size_t)jrow * Hv + k);
      wzh[kb] = cvt8(Whz1 + (size_t)jrow * Hv + k);
      wrh[kb] = cvt8(Whr1 + (size_t)jrow * Hv + k);
      if (OW) wo[kb] = cvt8(Why + (size_t)jrow * Hv + k);
    }
    float bz = bhz1[j0 + rj], br = bhr1[j0 + rj];
    float bo = OW ? by[j0 + rj] : 0.f;

    for (int t = 0; t < Sv; ++t) {
      // y0_t = h0 tag t+2 at slot (t+1)&m0; h1_t = tag t+1 at slot t&3
      poll2(h0s + ((t + 1) & m0) * 32, (unsigned)(t + 2),
            h1s + (t & 3) * 32, (unsigned)(t + 1), tid);
      const unsigned* yslot = h0d + (size_t)((t + 1) & m0) * 8192;
      const unsigned* hslot = h1d + (size_t)(t & 3) * 8192;
      float hval = ldhval_tag(hslot, wg, tid, (unsigned)(t + 1));
      v8bf ay[4], ahf[4];
      ldfrags_tag(yslot, wave, lm, lq, (unsigned)(t + 2), ay);
      ldfrags_tag(hslot, wave, lm, lq, (unsigned)(t + 1), ahf);
      v4f az = {0, 0, 0, 0}, axr = {0, 0, 0, 0}, ahr = {0, 0, 0, 0}, ao = {0, 0, 0, 0};
#pragma unroll
      for (int kb = 0; kb < 4; kb++) {
        az = MFMA(ay[kb], wzx1[kb], az);
        az = MFMA(ahf[kb], wzh[kb], az);
        axr = MFMA(ay[kb], wrx1[kb], axr);
        ahr = MFMA(ahf[kb], wrh[kb], ahr);
      }
      if (OW && t > 0) {
#pragma unroll
        for (int kb = 0; kb < 4; kb++) ao = MFMA(ahf[kb], wo[kb], ao);  // out_{t-1}
      }
#pragma unroll
      for (int v = 0; v < 4; v++) {
        red[0][wave][lq * 4 + v][lm] = az[v];
        red[1][wave][lq * 4 + v][lm] = axr[v];
        red[2][wave][lq * 4 + v][lm] = ahr[v];
        if (OW) red[3][wave][lq * 4 + v][lm] = ao[v];
      }
      __syncthreads();  // all waves' y0 fragment loads complete before this
      if (tid == 0) st32(prog + wg, (unsigned)(t + 1));
      float zs = 0, xrs = 0, hrs = 0, os = 0;
#pragma unroll
      for (int w = 0; w < 4; w++) {
        zs += red[0][w][rb][rj];
        xrs += red[1][w][rb][rj];
        hrs += red[2][w][rb][rj];
        if (OW) os += red[3][w][rb][rj];
      }
      float z = sigf(zs + bz);
      float r = sigf(xrs + hrs + br);
      store_val(u1d + (size_t)(t & 1) * 8192, wg, tid, r * hval, (unsigned)(t + 1));
      post(u1s + (t & 1) * 32, wg, (unsigned)(t + 1), tid);
      // out-store issued after the post: off the exchange chain
      if (OW && t > 0) out[((size_t)rb * Sv + (t - 1)) * Ov + j0 + rj] = os + bo;
      poll1(u1s + (t & 1) * 32, (unsigned)(t + 1), tid);
      v8bf au[4];
      ldfrags_tag(u1d + (size_t)(t & 1) * 8192, wave, lm, lq, (unsigned)(t + 1), au);
      v4f ag = {0, 0, 0, 0};
#pragma unroll
      for (int kb = 0; kb < 4; kb++) ag = MFMA(au[kb], wrh[kb], ag);
#pragma unroll
      for (int v = 0; v < 4; v++) red[4][wave][lq * 4 + v][lm] = ag[v];
      __syncthreads();
      float gs = 0;
#pragma unroll
      for (int w = 0; w < 4; w++) gs += red[4][w][rb][rj];
      float g = tanh_fast(xrs + gs + br);
      float hn = z * hval + (1.f - z) * g;
      store_val(h1d + (size_t)((t + 1) & 3) * 8192, wg, tid, hn, (unsigned)(t + 2));
      if (t == Sv - 1) out[(size_t)Bv * Sv * Ov + ((size_t)rb * 2 + 1) * Hv + j0 + rj] = hn;
      post(h1s + ((t + 1) & 3) * 32, wg, (unsigned)(t + 2), tid);
    }
    if (OW) {  // tail: out_{S-1} from y1_{S-1} = h1 tag S+1 at slot S&3
      poll1(h1s + (Sv & 3) * 32, (unsigned)(Sv + 1), tid);
      v8bf ah[4];
      ldfrags_tag(h1d + (size_t)(Sv & 3) * 8192, wave, lm, lq, (unsigned)(Sv + 1), ah);
      v4f ao = {0, 0, 0, 0};
#pragma unroll
      for (int kb = 0; kb < 4; kb++) ao = MFMA(ah[kb], wo[kb], ao);
#pragma unroll
      for (int v = 0; v < 4; v++) red[3][wave][lq * 4 + v][lm] = ao[v];
      __syncthreads();
      float os = 0;
#pragma unroll
      for (int w = 0; w < 4; w++) os += red[3][w][rb][rj];
      out[((size_t)rb * Sv + (Sv - 1)) * Ov + j0 + rj] = os + bo;
    }
  }
}

extern "C" void kernel_launch(void* const* d_in, const int* in_sizes, int n_in,
                              void* d_out, int out_size, void* d_ws, size_t ws_size,
                              hipStream_t stream) {
  const float* x = (const float*)d_in[0];
  const float* hs = (const float*)d_in[1];
  const float* Wxz0 = (const float*)d_in[2];
  const float* Whz0 = (const float*)d_in[3];
  const float* bhz0 = (const float*)d_in[4];
  const float* Wxr0 = (const float*)d_in[5];
  const float* Whr0 = (const float*)d_in[6];
  const float* bhr0 = (const float*)d_in[7];
  const float* Wxz1 = (const float*)d_in[8];
  const float* Whz1 = (const float*)d_in[9];
  const float* bhz1 = (const float*)d_in[10];
  const float* Wxr1 = (const float*)d_in[11];
  const float* Whr1 = (const float*)d_in[12];
  const float* bhr1 = (const float*)d_in[13];
  const float* Why = (const float*)d_in[14];
  const float* by = (const float*)d_in[15];
  float* out = (float*)d_out;

  // y0-ring depth: largest pow2 (<=64, >=4) fitting ws (32KB tagged slots)
  int D = 64;
  while (D > 4 && 16384 + (size_t)(D + 8) * 32768 > ws_size) D >>= 1;

  // zero prog + sentinels + ALL payload rings (tags must start != any step tag)
  size_t msz = 16384 + (size_t)(D + 8) * 32768;
  if (msz > ws_size) msz = ws_size;
  hipMemsetAsync(d_ws, 0, msz, stream);
  hipLaunchKernelGGL(gru_fused, dim3(64), dim3(256), 0, stream,
                     x, hs, Wxz0, Whz0, bhz0, Wxr0, Whr0, bhr0,
                     Wxz1, Whz1, bhz1, Wxr1, Whr1, bhr1, Why, by,
                     out, (char*)d_ws, D);
}

// Round 6
// 15012.572 us; speedup vs baseline: 1.1195x; 1.1195x over previous
//
#include <hip/hip_runtime.h>
#include <stdint.h>

// Problem constants
#define Bv 16
#define Sv 2048
#define Iv 128
#define Hv 512
#define Ov 128
#define RP 520  // staged LDS row pitch in ushorts

typedef __bf16 v8bf __attribute__((ext_vector_type(8)));
typedef float v4f __attribute__((ext_vector_type(4)));
#define MFMA(a, b, c) __builtin_amdgcn_mfma_f32_16x16x32_bf16((a), (b), (c), 0, 0, 0)

__device__ __forceinline__ float sigf(float x) { return 1.0f / (1.0f + __expf(-x)); }
__device__ __forceinline__ float tanh_fast(float x) { return 2.0f / (1.0f + __expf(-2.0f * x)) - 1.0f; }

__device__ __forceinline__ unsigned f2bf(float f) {
  union { __bf16 h; unsigned short u; } c; c.h = (__bf16)f; return (unsigned)c.u;
}
__device__ __forceinline__ float bf2f(unsigned short u) {
  union { __bf16 h; unsigned short u; } c; c.u = u; return (float)c.h;
}

__device__ __forceinline__ v8bf cvt8(const float* p) {
  v8bf r;
#pragma unroll
  for (int i = 0; i < 8; i++) r[i] = (__bf16)p[i];
  return r;
}

// LDS-only barrier: syncs threads + LDS ordering WITHOUT draining vmcnt.
// In-flight UC payload stores / global prefetch loads keep flying.
// Tag verification makes payload-visibility ordering unnecessary.
__device__ __forceinline__ void lgkm_barrier() {
  asm volatile("s_waitcnt lgkmcnt(0)\n\ts_barrier" ::: "memory");
}

// relaxed agent-scope atomics (bypass non-coherent per-XCD L2).
// Coherence point = Infinity Cache.
__device__ __forceinline__ uint64_t ld64(const uint64_t* p) {
  return __hip_atomic_load((uint64_t*)p, __ATOMIC_RELAXED, __HIP_MEMORY_SCOPE_AGENT);
}
__device__ __forceinline__ void st32(unsigned* p, unsigned v) {
  __hip_atomic_store(p, v, __ATOMIC_RELAXED, __HIP_MEMORY_SCOPE_AGENT);
}
__device__ __forceinline__ unsigned ld32(const unsigned* p) {
  return __hip_atomic_load((unsigned*)p, __ATOMIC_RELAXED, __HIP_MEMORY_SCOPE_AGENT);
}

// Tagged payload, BLOCK-MAJOR: slot = 8192 u32 (32KB). Block wg's chunk =
// 256 u32 (1KB) at wg*256; word [tid] = bf16(row tid>>4, col j0+(tid&15))
// | tag<<16. Producer store: 1 u32/thread, 8 dense lines per block.
__device__ __forceinline__ void store_val(unsigned* dslot, int wg, int tid, float val, unsigned tag) {
  st32(dslot + wg * 256 + tid, f2bf(val) | (tag << 16));
}

// Sentinel post: LDS-only barrier (all threads have ISSUED their payload
// stores; no visibility drain -- consumers verify per-word tags), then lane0
// posts one word.
__device__ __forceinline__ void post(unsigned* s, int idx, unsigned tag, int tid) {
  lgkm_barrier();
  if (tid == 0) st32(s + idx, tag);
}

// Poll 32 sentinel words (one 128B line) until all == want (hint only).
__device__ __forceinline__ void poll1(const unsigned* s, unsigned want, int tid) {
  unsigned r = 0;
  for (;;) {
    unsigned v = ld32(s + (tid & 31));
    if (__all(v == want) || ++r > (1u << 20)) break;  // valve: wrong beats hang
  }
}
__device__ __forceinline__ void poll2(const unsigned* sA, unsigned wA,
                                      const unsigned* sB, unsigned wB, int tid) {
  unsigned r = 0;
  for (;;) {
    unsigned a = ld32(sA + (tid & 31));
    unsigned b = ld32(sB + (tid & 31));
    if (__all((a == wA) && (b == wB)) || ++r > (1u << 20)) break;
  }
}

// One-shot DENSE payload read (32KB, ld64 at p + i*256 + tid: 512B contiguous
// per wave-instruction -- the only pattern this fabric runs fast), tag-verified
// in registers (retry on mismatch, rare), then strip tags -> LDS [16][RP].
// u64 q = i*256+tid -> rb=(q>>3)&15, col=(q>>7)*16+(q&7)*2.
__device__ __forceinline__ void read_stage_tag(const unsigned* dslot, unsigned short* lds,
                                               int tid, unsigned tag) {
  const uint64_t* p = (const uint64_t*)dslot;
  const uint64_t want = ((uint64_t)tag << 16) | ((uint64_t)tag << 48);
  const uint64_t MSK = 0xffff0000ffff0000ull;
  uint64_t w[16];
  unsigned r = 0;
  for (;;) {
    bool ok = true;
#pragma unroll
    for (int i = 0; i < 16; i++) {
      w[i] = ld64(p + i * 256 + tid);
      ok &= ((w[i] & MSK) == want);
    }
    if (__all(ok) || ++r > (1u << 18)) break;  // valve: wrong beats hang
    __builtin_amdgcn_s_sleep(1);
  }
#pragma unroll
  for (int i = 0; i < 16; i++) {
    int q = i * 256 + tid;
    unsigned pk = (unsigned)(w[i] & 0xffffu) | ((unsigned)(w[i] >> 32) << 16);
    *(uint32_t*)(lds + ((q >> 3) & 15) * RP + (q >> 7) * 16 + (q & 7) * 2) = pk;
  }
}
// Dual version: both slots' loads in flight together; selective retry.
__device__ __forceinline__ void read_stage2_tag(const unsigned* dA, unsigned short* lA, unsigned tagA,
                                                const unsigned* dB, unsigned short* lB, unsigned tagB,
                                                int tid) {
  const uint64_t* pA = (const uint64_t*)dA;
  const uint64_t* pB = (const uint64_t*)dB;
  const uint64_t wantA = ((uint64_t)tagA << 16) | ((uint64_t)tagA << 48);
  const uint64_t wantB = ((uint64_t)tagB << 16) | ((uint64_t)tagB << 48);
  const uint64_t MSK = 0xffff0000ffff0000ull;
  uint64_t wa[16], wb[16];
  bool dAok = false, dBok = false;
  unsigned r = 0;
  for (;;) {
    if (!dAok) {
      bool ok = true;
#pragma unroll
      for (int i = 0; i < 16; i++) {
        wa[i] = ld64(pA + i * 256 + tid);
        ok &= ((wa[i] & MSK) == wantA);
      }
      dAok = __all(ok);
    }
    if (!dBok) {
      bool ok = true;
#pragma unroll
      for (int i = 0; i < 16; i++) {
        wb[i] = ld64(pB + i * 256 + tid);
        ok &= ((wb[i] & MSK) == wantB);
      }
      dBok = __all(ok);
    }
    if ((dAok && dBok) || ++r > (1u << 18)) break;
    __builtin_amdgcn_s_sleep(1);
  }
#pragma unroll
  for (int i = 0; i < 16; i++) {
    int q = i * 256 + tid;
    int off = ((q >> 3) & 15) * RP + (q >> 7) * 16 + (q & 7) * 2;
    *(uint32_t*)(lA + off) = (unsigned)(wa[i] & 0xffffu) | ((unsigned)(wa[i] >> 32) << 16);
    *(uint32_t*)(lB + off) = (unsigned)(wb[i] & 0xffffu) | ((unsigned)(wb[i] >> 32) << 16);
  }
}

__global__ __launch_bounds__(256, 1) void gru_fused(
    const float* __restrict__ x, const float* __restrict__ hs,
    const float* __restrict__ Wxz0, const float* __restrict__ Whz0, const float* __restrict__ bhz0,
    const float* __restrict__ Wxr0, const float* __restrict__ Whr0, const float* __restrict__ bhr0,
    const float* __restrict__ Wxz1, const float* __restrict__ Whz1, const float* __restrict__ bhz1,
    const float* __restrict__ Wxr1, const float* __restrict__ Whr1, const float* __restrict__ bhr1,
    const float* __restrict__ Why, const float* __restrict__ by,
    float* __restrict__ out, char* __restrict__ ws, int D) {
  const int tid = threadIdx.x;
  const int wave = tid >> 6;
  const int lane = tid & 63;
  const int lm = lane & 15;
  const int lq = lane >> 4;
  const int rb = tid >> 4;
  const int rj = tid & 15;
  const int m0 = D - 1;

  unsigned* prog = (unsigned*)ws;  // [32], zeroed by memset
  unsigned* h0s = (unsigned*)(ws + 1024);  // [D][32] sentinels
  unsigned* h1s = h0s + D * 32;            // [4][32]
  unsigned* u0s = h1s + 128;               // [2][32]
  unsigned* u1s = u0s + 64;                // [2][32]
  unsigned* h0d = (unsigned*)(ws + 16384); // [D][8192] tagged payload (32KB/slot)
  unsigned* h1d = h0d + (size_t)D * 8192;  // [4][8192]
  unsigned* u0d = h1d + 4 * 8192;          // [2][8192]
  unsigned* u1d = u0d + 2 * 8192;          // [2][8192]

  __shared__ unsigned short stA[16 * RP];
  __shared__ unsigned short stB[16 * RP];
  __shared__ unsigned short stC[16 * RP];
  __shared__ float red[5][4][16][17];  // planes: 0=z 1=xr 2=hr 3=out 4=g

  const bool L0 = (blockIdx.x < 32);
  const int wg = L0 ? blockIdx.x : (blockIdx.x - 32);
  const int j0 = wg << 4;
  const bool OW = (!L0) && (wg < 8);
  const int jrow = j0 + lm;

  // ---- initial hidden state -> payload slot 0 (tag 1), sentinel 1 ----
  {
    float h0v = hs[((size_t)rb * 2 + (L0 ? 0 : 1)) * Hv + j0 + rj];
    store_val(L0 ? h0d : h1d, wg, tid, h0v, 1u);
    post(L0 ? h0s : h1s, wg, 1u, tid);
  }

  if (L0) {
    v8bf wzx0 = cvt8(Wxz0 + (size_t)jrow * Iv + wave * 32 + lq * 8);
    v8bf wrx0 = cvt8(Wxr0 + (size_t)jrow * Iv + wave * 32 + lq * 8);
    v8bf wzh[4], wrh[4];
#pragma unroll
    for (int kb = 0; kb < 4; kb++) {
      int k = wave * 128 + kb * 32 + lq * 8;
      wzh[kb] = cvt8(Whz0 + (size_t)jrow * Hv + k);
      wrh[kb] = cvt8(Whr0 + (size_t)jrow * Hv + k);
    }
    float bz = bhz0[j0 + rj], br = bhr0[j0 + rj];

    const int xk = wave * 32 + lq * 8;
    float4 xp0 = *(const float4*)(x + ((size_t)lm * Sv + 0) * Iv + xk);
    float4 xp1 = *(const float4*)(x + ((size_t)lm * Sv + 0) * Iv + xk + 4);

    for (int t = 0; t < Sv; ++t) {
      if (t >= D - 1 && tid < 32) {  // backpressure vs L1's y0 consumption
        unsigned need = (unsigned)(t - D + 2), it = 0;
        while (ld32(prog + tid) < need)
          if (++it > (1u << 20)) break;
      }
      poll1(h0s + (t & m0) * 32, (unsigned)(t + 1), tid);
      read_stage_tag(h0d + (size_t)(t & m0) * 8192, stA, tid, (unsigned)(t + 1));
      lgkm_barrier();  // B1: stage visible
      float hval = bf2f(stA[rb * RP + j0 + rj]);
      const unsigned short* hrow = stA + lm * RP;
      v8bf ah[4];
#pragma unroll
      for (int kb = 0; kb < 4; kb++)
        ah[kb] = *(const v8bf*)(hrow + wave * 128 + kb * 32 + lq * 8);
      v8bf ax;
      {
        float xf[8] = {xp0.x, xp0.y, xp0.z, xp0.w, xp1.x, xp1.y, xp1.z, xp1.w};
#pragma unroll
        for (int i = 0; i < 8; i++) ax[i] = (__bf16)xf[i];
      }
      v4f az = {0, 0, 0, 0}, axr = {0, 0, 0, 0}, ahr = {0, 0, 0, 0};
      az = MFMA(ax, wzx0, az);
      axr = MFMA(ax, wrx0, axr);
#pragma unroll
      for (int kb = 0; kb < 4; kb++) {
        az = MFMA(ah[kb], wzh[kb], az);
        ahr = MFMA(ah[kb], wrh[kb], ahr);
      }
#pragma unroll
      for (int v = 0; v < 4; v++) {
        red[0][wave][lq * 4 + v][lm] = az[v];
        red[1][wave][lq * 4 + v][lm] = axr[v];
        red[2][wave][lq * 4 + v][lm] = ahr[v];
      }
      lgkm_barrier();  // B2: red visible
      float zs = 0, xrs = 0, hrs = 0;
#pragma unroll
      for (int w = 0; w < 4; w++) {
        zs += red[0][w][rb][rj];
        xrs += red[1][w][rb][rj];
        hrs += red[2][w][rb][rj];
      }
      float z = sigf(zs + bz);
      float r = sigf(xrs + hrs + br);
      store_val(u0d + (size_t)(t & 1) * 8192, wg, tid, r * hval, (unsigned)(t + 1));
      if (t + 1 < Sv) {  // prefetch next x (overlaps the u-hop)
        xp0 = *(const float4*)(x + ((size_t)lm * Sv + (t + 1)) * Iv + xk);
        xp1 = *(const float4*)(x + ((size_t)lm * Sv + (t + 1)) * Iv + xk + 4);
      }
      post(u0s + (t & 1) * 32, wg, (unsigned)(t + 1), tid);  // B3 (no vm drain)
      poll1(u0s + (t & 1) * 32, (unsigned)(t + 1), tid);
      read_stage_tag(u0d + (size_t)(t & 1) * 8192, stB, tid, (unsigned)(t + 1));
      lgkm_barrier();  // B4
      const unsigned short* urow = stB + lm * RP;
      v4f ag = {0, 0, 0, 0};
#pragma unroll
      for (int kb = 0; kb < 4; kb++) {
        v8bf au = *(const v8bf*)(urow + wave * 128 + kb * 32 + lq * 8);
        ag = MFMA(au, wrh[kb], ag);
      }
#pragma unroll
      for (int v = 0; v < 4; v++) red[4][wave][lq * 4 + v][lm] = ag[v];
      lgkm_barrier();  // B5
      float gs = 0;
#pragma unroll
      for (int w = 0; w < 4; w++) gs += red[4][w][rb][rj];
      float g = tanh_fast(xrs + gs + br);  // faithful to source bug
      float hn = z * hval + (1.f - z) * g;
      store_val(h0d + (size_t)((t + 1) & m0) * 8192, wg, tid, hn, (unsigned)(t + 2));
      if (t == Sv - 1) out[(size_t)Bv * Sv * Ov + ((size_t)rb * 2 + 0) * Hv + j0 + rj] = hn;
      post(h0s + ((t + 1) & m0) * 32, wg, (unsigned)(t + 2), tid);  // B6 (no vm drain)
    }
  } else {
    v8bf wzx1[4], wrx1[4], wzh[4], wrh[4], wo[4];
#pragma unroll
    for (int kb = 0; kb < 4; kb++) {
      int k = wave * 128 + kb * 32 + lq * 8;
      wzx1[kb] = cvt8(Wxz1 + (size_t)jrow * Hv + k);
      wrx1[kb] = cvt8(Wxr1 + (size_t)jrow * Hv + k);
      wzh[kb] = cvt8(Whz1 + (size_t)jrow * Hv + k);
      wrh[kb] = cvt8(Whr1 + (size_t)jrow * Hv + k);
      if (OW) wo[kb] = cvt8(Why + (size_t)jrow * Hv + k);
    }
    float bz = bhz1[j0 + rj], br = bhr1[j0 + rj];
    float bo = OW ? by[j0 + rj] : 0.f;

    for (int t = 0; t < Sv; ++t) {
      // y0_t = h0 tag t+2 at slot (t+1)&m0; h1_t = tag t+1 at slot t&3
      poll2(h0s + ((t + 1) & m0) * 32, (unsigned)(t + 2),
            h1s + (t & 3) * 32, (unsigned)(t + 1), tid);
      read_stage2_tag(h0d + (size_t)((t + 1) & m0) * 8192, stA, (unsigned)(t + 2),
                      h1d + (size_t)(t & 3) * 8192, stB, (unsigned)(t + 1), tid);
      lgkm_barrier();  // B1: all threads' y0 reads verified + staged
      if (tid == 0) st32(prog + wg, (unsigned)(t + 1));  // y0_t consumed: unblock L0
      float hval = bf2f(stB[rb * RP + j0 + rj]);
      const unsigned short* yrow = stA + lm * RP;
      const unsigned short* hrow = stB + lm * RP;
      v4f az = {0, 0, 0, 0}, axr = {0, 0, 0, 0}, ahr = {0, 0, 0, 0}, ao = {0, 0, 0, 0};
      v8bf ahf[4];
#pragma unroll
      for (int kb = 0; kb < 4; kb++) {
        int k = wave * 128 + kb * 32 + lq * 8;
        v8bf ay = *(const v8bf*)(yrow + k);
        ahf[kb] = *(const v8bf*)(hrow + k);
        az = MFMA(ay, wzx1[kb], az);
        az = MFMA(ahf[kb], wzh[kb], az);
        axr = MFMA(ay, wrx1[kb], axr);
        ahr = MFMA(ahf[kb], wrh[kb], ahr);
      }
      if (OW && t > 0) {
#pragma unroll
        for (int kb = 0; kb < 4; kb++) ao = MFMA(ahf[kb], wo[kb], ao);  // out_{t-1}
      }
#pragma unroll
      for (int v = 0; v < 4; v++) {
        red[0][wave][lq * 4 + v][lm] = az[v];
        red[1][wave][lq * 4 + v][lm] = axr[v];
        red[2][wave][lq * 4 + v][lm] = ahr[v];
        if (OW) red[3][wave][lq * 4 + v][lm] = ao[v];
      }
      lgkm_barrier();  // B2
      float zs = 0, xrs = 0, hrs = 0, os = 0;
#pragma unroll
      for (int w = 0; w < 4; w++) {
        zs += red[0][w][rb][rj];
        xrs += red[1][w][rb][rj];
        hrs += red[2][w][rb][rj];
        if (OW) os += red[3][w][rb][rj];
      }
      float z = sigf(zs + bz);
      float r = sigf(xrs + hrs + br);
      store_val(u1d + (size_t)(t & 1) * 8192, wg, tid, r * hval, (unsigned)(t + 1));
      post(u1s + (t & 1) * 32, wg, (unsigned)(t + 1), tid);  // B3 (no vm drain)
      // out-store issued after the post: off the exchange chain
      if (OW && t > 0) out[((size_t)rb * Sv + (t - 1)) * Ov + j0 + rj] = os + bo;
      poll1(u1s + (t & 1) * 32, (unsigned)(t + 1), tid);
      read_stage_tag(u1d + (size_t)(t & 1) * 8192, stC, tid, (unsigned)(t + 1));
      lgkm_barrier();  // B4
      const unsigned short* urow = stC + lm * RP;
      v4f ag = {0, 0, 0, 0};
#pragma unroll
      for (int kb = 0; kb < 4; kb++) {
        v8bf au = *(const v8bf*)(urow + wave * 128 + kb * 32 + lq * 8);
        ag = MFMA(au, wrh[kb], ag);
      }
#pragma unroll
      for (int v = 0; v < 4; v++) red[4][wave][lq * 4 + v][lm] = ag[v];
      lgkm_barrier();  // B5
      float gs = 0;
#pragma unroll
      for (int w = 0; w < 4; w++) gs += red[4][w][rb][rj];
      float g = tanh_fast(xrs + gs + br);
      float hn = z * hval + (1.f - z) * g;
      store_val(h1d + (size_t)((t + 1) & 3) * 8192, wg, tid, hn, (unsigned)(t + 2));
      if (t == Sv - 1) out[(size_t)Bv * Sv * Ov + ((size_t)rb * 2 + 1) * Hv + j0 + rj] = hn;
      post(h1s + ((t + 1) & 3) * 32, wg, (unsigned)(t + 2), tid);  // B6 (no vm drain)
    }
    if (OW) {  // tail: out_{S-1} from y1_{S-1} = h1 tag S+1 at slot S&3
      poll1(h1s + (Sv & 3) * 32, (unsigned)(Sv + 1), tid);
      read_stage_tag(h1d + (size_t)(Sv & 3) * 8192, stB, tid, (unsigned)(Sv + 1));
      lgkm_barrier();
      const unsigned short* hrow = stB + lm * RP;
      v4f ao = {0, 0, 0, 0};
#pragma unroll
      for (int kb = 0; kb < 4; kb++) {
        v8bf ah = *(const v8bf*)(hrow + wave * 128 + kb * 32 + lq * 8);
        ao = MFMA(ah, wo[kb], ao);
      }
#pragma unroll
      for (int v = 0; v < 4; v++) red[3][wave][lq * 4 + v][lm] = ao[v];
      lgkm_barrier();
      float os = 0;
#pragma unroll
      for (int w = 0; w < 4; w++) os += red[3][w][rb][rj];
      out[((size_t)rb * Sv + (Sv - 1)) * Ov + j0 + rj] = os + bo;
    }
  }
}

extern "C" void kernel_launch(void* const* d_in, const int* in_sizes, int n_in,
                              void* d_out, int out_size, void* d_ws, size_t ws_size,
                              hipStream_t stream) {
  const float* x = (const float*)d_in[0];
  const float* hs = (const float*)d_in[1];
  const float* Wxz0 = (const float*)d_in[2];
  const float* Whz0 = (const float*)d_in[3];
  const float* bhz0 = (const float*)d_in[4];
  const float* Wxr0 = (const float*)d_in[5];
  const float* Whr0 = (const float*)d_in[6];
  const float* bhr0 = (const float*)d_in[7];
  const float* Wxz1 = (const float*)d_in[8];
  const float* Whz1 = (const float*)d_in[9];
  const float* bhz1 = (const float*)d_in[10];
  const float* Wxr1 = (const float*)d_in[11];
  const float* Whr1 = (const float*)d_in[12];
  const float* bhr1 = (const float*)d_in[13];
  const float* Why = (const float*)d_in[14];
  const float* by = (const float*)d_in[15];
  float* out = (float*)d_out;

  // y0-ring depth: largest pow2 (<=64, >=4) fitting ws (32KB tagged slots)
  int D = 64;
  while (D > 4 && 16384 + (size_t)(D + 8) * 32768 > ws_size) D >>= 1;

  // zero prog + sentinels + ALL payload rings (tags must start != any step tag)
  size_t msz = 16384 + (size_t)(D + 8) * 32768;
  if (msz > ws_size) msz = ws_size;
  hipMemsetAsync(d_ws, 0, msz, stream);
  hipLaunchKernelGGL(gru_fused, dim3(64), dim3(256), 0, stream,
                     x, hs, Wxz0, Whz0, bhz0, Wxr0, Whr0, bhr0,
                     Wxz1, Whz1, bhz1, Wxr1, Whr1, bhr1, Why, by,
                     out, (char*)d_ws, D);
}

// Round 7
// 11407.945 us; speedup vs baseline: 1.4733x; 1.3160x over previous
//
#include <hip/hip_runtime.h>
#include <stdint.h>

// Problem constants
#define Bv 16
#define Sv 2048
#define Iv 128
#define Hv 512
#define Ov 128
#define RP 520  // staged LDS row pitch in ushorts

typedef __bf16 v8bf __attribute__((ext_vector_type(8)));
typedef float v4f __attribute__((ext_vector_type(4)));
#define MFMA(a, b, c) __builtin_amdgcn_mfma_f32_16x16x32_bf16((a), (b), (c), 0, 0, 0)

__device__ __forceinline__ float sigf(float x) { return 1.0f / (1.0f + __expf(-x)); }
__device__ __forceinline__ float tanh_fast(float x) { return 2.0f / (1.0f + __expf(-2.0f * x)) - 1.0f; }

__device__ __forceinline__ unsigned f2bf(float f) {
  union { __bf16 h; unsigned short u; } c; c.h = (__bf16)f; return (unsigned)c.u;
}
__device__ __forceinline__ float bf2f(unsigned short u) {
  union { __bf16 h; unsigned short u; } c; c.u = u; return (float)c.h;
}

__device__ __forceinline__ v8bf cvt8(const float* p) {
  v8bf r;
#pragma unroll
  for (int i = 0; i < 8; i++) r[i] = (__bf16)p[i];
  return r;
}

// LDS-only barrier: syncs threads + LDS ordering WITHOUT draining vmcnt.
__device__ __forceinline__ void lgkm_barrier() {
  asm volatile("s_waitcnt lgkmcnt(0)\n\ts_barrier" ::: "memory");
}

// relaxed agent-scope atomics; consumers verify freshness via inline tags.
__device__ __forceinline__ uint64_t ld64(const uint64_t* p) {
  return __hip_atomic_load((uint64_t*)p, __ATOMIC_RELAXED, __HIP_MEMORY_SCOPE_AGENT);
}
__device__ __forceinline__ void st32(unsigned* p, unsigned v) {
  __hip_atomic_store(p, v, __ATOMIC_RELAXED, __HIP_MEMORY_SCOPE_AGENT);
}
__device__ __forceinline__ unsigned ld32(const unsigned* p) {
  return __hip_atomic_load((unsigned*)p, __ATOMIC_RELAXED, __HIP_MEMORY_SCOPE_AGENT);
}

// Tagged payload, CHUNK-MAJOR: slot = 8192 u32 (32KB). Legacy column-group
// `oldwg` (0..31) owns 256 u32 (1KB) at oldwg*256; word [gtid] =
// bf16(row gtid>>4, col j0+(gtid&15)) | tag<<16. 1 dense u32/thread.
__device__ __forceinline__ void store_val(unsigned* dslot, int oldwg, int gtid, float val, unsigned tag) {
  st32(dslot + oldwg * 256 + gtid, f2bf(val) | (tag << 16));
}

// Sentinel post for a PACKED block (two groups): LDS-only barrier (stores
// issued; no visibility drain -- tags verify), then tid0 posts both words.
__device__ __forceinline__ void post2(unsigned* s, int p, unsigned tag, int tid) {
  lgkm_barrier();
  if (tid == 0) { st32(s + 2 * p, tag); st32(s + 2 * p + 1, tag); }
}

// Poll 32 sentinel words (one 128B line) until all == want (hint only).
// Slow path: occasional acquire fence to defeat any stale cached line.
__device__ __forceinline__ void poll1(const unsigned* s, unsigned want, int tid) {
  unsigned r = 0;
  for (;;) {
    unsigned v = ld32(s + (tid & 31));
    if (__all(v == want) || ++r > (1u << 20)) break;  // valve: wrong beats hang
    if ((r & 4095) == 4095) __builtin_amdgcn_fence(__ATOMIC_ACQUIRE, "agent");
  }
}
__device__ __forceinline__ void poll2(const unsigned* sA, unsigned wA,
                                      const unsigned* sB, unsigned wB, int tid) {
  unsigned r = 0;
  for (;;) {
    unsigned a = ld32(sA + (tid & 31));
    unsigned b = ld32(sB + (tid & 31));
    if (__all((a == wA) && (b == wB)) || ++r > (1u << 20)) break;
    if ((r & 4095) == 4095) __builtin_amdgcn_fence(__ATOMIC_ACQUIRE, "agent");
  }
}

// One-shot DENSE payload read (32KB via ld64 at p + i*512 + tid: 512B+
// contiguous per wave-instruction), tag-verified in registers (retry rare;
// acquire fence on retry guarantees progress), strip tags -> LDS [16][RP].
// u64 q: chunk=q>>7, rb=(q>>3)&15, cols=(q>>7)*16+(q&7)*2.
__device__ __forceinline__ void read_stage_tag(const unsigned* dslot, unsigned short* lds,
                                               int tid, unsigned tag) {
  const uint64_t* p = (const uint64_t*)dslot;
  const uint64_t want = ((uint64_t)tag << 16) | ((uint64_t)tag << 48);
  const uint64_t MSK = 0xffff0000ffff0000ull;
  uint64_t w[8];
  unsigned r = 0;
  for (;;) {
    bool ok = true;
#pragma unroll
    for (int i = 0; i < 8; i++) {
      w[i] = ld64(p + i * 512 + tid);
      ok &= ((w[i] & MSK) == want);
    }
    if (__all(ok) || ++r > (1u << 18)) break;  // valve: wrong beats hang
    __builtin_amdgcn_fence(__ATOMIC_ACQUIRE, "agent");
    __builtin_amdgcn_s_sleep(1);
  }
#pragma unroll
  for (int i = 0; i < 8; i++) {
    int q = i * 512 + tid;
    unsigned pk = (unsigned)(w[i] & 0xffffu) | ((unsigned)(w[i] >> 32) << 16);
    *(uint32_t*)(lds + ((q >> 3) & 15) * RP + (q >> 7) * 16 + (q & 7) * 2) = pk;
  }
}
__device__ __forceinline__ void read_stage2_tag(const unsigned* dA, unsigned short* lA, unsigned tagA,
                                                const unsigned* dB, unsigned short* lB, unsigned tagB,
                                                int tid) {
  const uint64_t* pA = (const uint64_t*)dA;
  const uint64_t* pB = (const uint64_t*)dB;
  const uint64_t wantA = ((uint64_t)tagA << 16) | ((uint64_t)tagA << 48);
  const uint64_t wantB = ((uint64_t)tagB << 16) | ((uint64_t)tagB << 48);
  const uint64_t MSK = 0xffff0000ffff0000ull;
  uint64_t wa[8], wb[8];
  bool dAok = false, dBok = false;
  unsigned r = 0;
  for (;;) {
    if (!dAok) {
      bool ok = true;
#pragma unroll
      for (int i = 0; i < 8; i++) {
        wa[i] = ld64(pA + i * 512 + tid);
        ok &= ((wa[i] & MSK) == wantA);
      }
      dAok = __all(ok);
    }
    if (!dBok) {
      bool ok = true;
#pragma unroll
      for (int i = 0; i < 8; i++) {
        wb[i] = ld64(pB + i * 512 + tid);
        ok &= ((wb[i] & MSK) == wantB);
      }
      dBok = __all(ok);
    }
    if ((dAok && dBok) || ++r > (1u << 18)) break;
    __builtin_amdgcn_fence(__ATOMIC_ACQUIRE, "agent");
    __builtin_amdgcn_s_sleep(1);
  }
#pragma unroll
  for (int i = 0; i < 8; i++) {
    int q = i * 512 + tid;
    int off = ((q >> 3) & 15) * RP + (q >> 7) * 16 + (q & 7) * 2;
    *(uint32_t*)(lA + off) = (unsigned)(wa[i] & 0xffffu) | ((unsigned)(wa[i] >> 32) << 16);
    *(uint32_t*)(lB + off) = (unsigned)(wb[i] & 0xffffu) | ((unsigned)(wb[i] >> 32) << 16);
  }
}

__global__ __launch_bounds__(512, 1) void gru_fused(
    const float* __restrict__ x, const float* __restrict__ hs,
    const float* __restrict__ Wxz0, const float* __restrict__ Whz0, const float* __restrict__ bhz0,
    const float* __restrict__ Wxr0, const float* __restrict__ Whr0, const float* __restrict__ bhr0,
    const float* __restrict__ Wxz1, const float* __restrict__ Whz1, const float* __restrict__ bhz1,
    const float* __restrict__ Wxr1, const float* __restrict__ Whr1, const float* __restrict__ bhr1,
    const float* __restrict__ Why, const float* __restrict__ by,
    float* __restrict__ out, char* __restrict__ ws, int D) {
  const int tid = threadIdx.x;
  const int g = tid >> 8;      // column-group within packed block (0/1)
  const int gtid = tid & 255;  // thread id within group
  const int wig = gtid >> 6;   // wave within group (0..3) = K-split
  const int lane = tid & 63;
  const int lm = lane & 15;
  const int lq = lane >> 4;
  const int rb = gtid >> 4;    // batch row
  const int rj = gtid & 15;    // col within group's 16-col slice
  const int m0 = D - 1;

  unsigned* prog = (unsigned*)ws;            // [32], zeroed by memset
  unsigned* claim = (unsigned*)(ws + 512);   // worker-role counter
  unsigned* h0s = (unsigned*)(ws + 1024);    // [D][32] sentinels
  unsigned* h1s = h0s + D * 32;              // [4][32]
  unsigned* u0s = h1s + 128;                 // [2][32]
  unsigned* u1s = u0s + 64;                  // [2][32]
  unsigned* h0d = (unsigned*)(ws + 16384);   // [D][8192] tagged payload (32KB)
  unsigned* h1d = h0d + (size_t)D * 8192;    // [4][8192]
  unsigned* u0d = h1d + 4 * 8192;            // [2][8192]
  unsigned* u1d = u0d + 2 * 8192;            // [2][8192]

  __shared__ unsigned short stA[16 * RP];
  __shared__ unsigned short stB[16 * RP];
  __shared__ unsigned short stC[16 * RP];
  __shared__ float red[2][5][4][16][17];  // [group][plane: z,xr,hr,out,g]
  __shared__ unsigned role_s;

  // ---- XCD co-location: blocks on XCD 0 claim the 32 worker roles; others
  // wait ~100us then claim any unfilled roles (correctness fallback), else exit.
  if (tid == 0) {
    unsigned xcc = 0;
    asm volatile("s_getreg_b32 %0, hwreg(HW_REG_XCC_ID)" : "=s"(xcc));
    unsigned role = 0xffffffffu;
    if ((xcc & 7) == 0) {
      role = __hip_atomic_fetch_add(claim, 1u, __ATOMIC_RELAXED, __HIP_MEMORY_SCOPE_AGENT);
    } else {
      for (int i = 0; i < 32; i++) __builtin_amdgcn_s_sleep(127);  // ~100us
      if (ld32(claim) < 32)
        role = __hip_atomic_fetch_add(claim, 1u, __ATOMIC_RELAXED, __HIP_MEMORY_SCOPE_AGENT);
    }
    role_s = role;
  }
  __syncthreads();
  const unsigned role = role_s;
  if (role >= 32) return;  // dummy block

  const bool L0 = (role < 16);
  const int p = L0 ? (int)role : (int)role - 16;  // packed index within layer
  const int oldwg = p * 2 + g;                    // legacy 16-col group id (0..31)
  const int j0 = oldwg << 4;
  const bool OW = (!L0) && (p < 4);               // oldwg 0..7 own output cols
  const int jrow = j0 + lm;

  // ---- initial hidden state -> payload slot 0 (tag 1), sentinels 1 ----
  {
    float h0v = hs[((size_t)rb * 2 + (L0 ? 0 : 1)) * Hv + j0 + rj];
    store_val(L0 ? h0d : h1d, oldwg, gtid, h0v, 1u);
    post2(L0 ? h0s : h1s, p, 1u, tid);
  }

  if (L0) {
    const int xk = wig * 32 + lq * 8;
    v8bf wzx0 = cvt8(Wxz0 + (size_t)jrow * Iv + xk);
    v8bf wrx0 = cvt8(Wxr0 + (size_t)jrow * Iv + xk);
    v8bf wzh[4], wrh[4];
#pragma unroll
    for (int kb = 0; kb < 4; kb++) {
      int k = wig * 128 + kb * 32 + lq * 8;
      wzh[kb] = cvt8(Whz0 + (size_t)jrow * Hv + k);
      wrh[kb] = cvt8(Whr0 + (size_t)jrow * Hv + k);
    }
    float bz = bhz0[j0 + rj], br = bhr0[j0 + rj];

    float4 xp0 = *(const float4*)(x + ((size_t)lm * Sv + 0) * Iv + xk);
    float4 xp1 = *(const float4*)(x + ((size_t)lm * Sv + 0) * Iv + xk + 4);

    for (int t = 0; t < Sv; ++t) {
      if (t >= D - 1 && tid < 32) {  // backpressure vs L1's y0 consumption
        unsigned need = (unsigned)(t - D + 2), it = 0;
        while (ld32(prog + tid) < need)
          if (++it > (1u << 20)) break;
      }
      poll1(h0s + (t & m0) * 32, (unsigned)(t + 1), tid);
      read_stage_tag(h0d + (size_t)(t & m0) * 8192, stA, tid, (unsigned)(t + 1));
      lgkm_barrier();  // B1: stage visible
      float hval = bf2f(stA[rb * RP + j0 + rj]);
      const unsigned short* hrow = stA + lm * RP;
      v8bf ah[4];
#pragma unroll
      for (int kb = 0; kb < 4; kb++)
        ah[kb] = *(const v8bf*)(hrow + wig * 128 + kb * 32 + lq * 8);
      v8bf ax;
      {
        float xf[8] = {xp0.x, xp0.y, xp0.z, xp0.w, xp1.x, xp1.y, xp1.z, xp1.w};
#pragma unroll
        for (int i = 0; i < 8; i++) ax[i] = (__bf16)xf[i];
      }
      v4f az = {0, 0, 0, 0}, axr = {0, 0, 0, 0}, ahr = {0, 0, 0, 0};
      az = MFMA(ax, wzx0, az);
      axr = MFMA(ax, wrx0, axr);
#pragma unroll
      for (int kb = 0; kb < 4; kb++) {
        az = MFMA(ah[kb], wzh[kb], az);
        ahr = MFMA(ah[kb], wrh[kb], ahr);
      }
#pragma unroll
      for (int v = 0; v < 4; v++) {
        red[g][0][wig][lq * 4 + v][lm] = az[v];
        red[g][1][wig][lq * 4 + v][lm] = axr[v];
        red[g][2][wig][lq * 4 + v][lm] = ahr[v];
      }
      lgkm_barrier();  // B2
      float zs = 0, xrs = 0, hrs = 0;
#pragma unroll
      for (int w = 0; w < 4; w++) {
        zs += red[g][0][w][rb][rj];
        xrs += red[g][1][w][rb][rj];
        hrs += red[g][2][w][rb][rj];
      }
      float z = sigf(zs + bz);
      float r = sigf(xrs + hrs + br);
      store_val(u0d + (size_t)(t & 1) * 8192, oldwg, gtid, r * hval, (unsigned)(t + 1));
      if (t + 1 < Sv) {  // prefetch next x (overlaps the u-hop)
        xp0 = *(const float4*)(x + ((size_t)lm * Sv + (t + 1)) * Iv + xk);
        xp1 = *(const float4*)(x + ((size_t)lm * Sv + (t + 1)) * Iv + xk + 4);
      }
      post2(u0s + (t & 1) * 32, p, (unsigned)(t + 1), tid);  // B3 (no vm drain)
      poll1(u0s + (t & 1) * 32, (unsigned)(t + 1), tid);
      read_stage_tag(u0d + (size_t)(t & 1) * 8192, stB, tid, (unsigned)(t + 1));
      lgkm_barrier();  // B4
      const unsigned short* urow = stB + lm * RP;
      v4f ag = {0, 0, 0, 0};
#pragma unroll
      for (int kb = 0; kb < 4; kb++) {
        v8bf au = *(const v8bf*)(urow + wig * 128 + kb * 32 + lq * 8);
        ag = MFMA(au, wrh[kb], ag);
      }
#pragma unroll
      for (int v = 0; v < 4; v++) red[g][4][wig][lq * 4 + v][lm] = ag[v];
      lgkm_barrier();  // B5
      float gs = 0;
#pragma unroll
      for (int w = 0; w < 4; w++) gs += red[g][4][w][rb][rj];
      float gg = tanh_fast(xrs + gs + br);  // faithful to source bug
      float hn = z * hval + (1.f - z) * gg;
      store_val(h0d + (size_t)((t + 1) & m0) * 8192, oldwg, gtid, hn, (unsigned)(t + 2));
      if (t == Sv - 1) out[(size_t)Bv * Sv * Ov + ((size_t)rb * 2 + 0) * Hv + j0 + rj] = hn;
      post2(h0s + ((t + 1) & m0) * 32, p, (unsigned)(t + 2), tid);  // B6 (no vm drain)
    }
  } else {
    v8bf wzx1[4], wrx1[4], wzh[4], wrh[4], wo[4];
#pragma unroll
    for (int kb = 0; kb < 4; kb++) {
      int k = wig * 128 + kb * 32 + lq * 8;
      wzx1[kb] = cvt8(Wxz1 + (size_t)jrow * Hv + k);
      wrx1[kb] = cvt8(Wxr1 + (size_t)jrow * Hv + k);
      wzh[kb] = cvt8(Whz1 + (size_t)jrow * Hv + k);
      wrh[kb] = cvt8(Whr1 + (size_t)jrow * Hv + k);
      if (OW) wo[kb] = cvt8(Why + (size_t)jrow * Hv + k);
    }
    float bz = bhz1[j0 + rj], br = bhr1[j0 + rj];
    float bo = OW ? by[j0 + rj] : 0.f;

    for (int t = 0; t < Sv; ++t) {
      // y0_t = h0 tag t+2 at slot (t+1)&m0; h1_t = tag t+1 at slot t&3
      poll2(h0s + ((t + 1) & m0) * 32, (unsigned)(t + 2),
            h1s + (t & 3) * 32, (unsigned)(t + 1), tid);
      read_stage2_tag(h0d + (size_t)((t + 1) & m0) * 8192, stA, (unsigned)(t + 2),
                      h1d + (size_t)(t & 3) * 8192, stB, (unsigned)(t + 1), tid);
      lgkm_barrier();  // B1: y0 reads verified + staged
      if (tid == 0) {  // y0_t consumed: unblock L0
        st32(prog + 2 * p, (unsigned)(t + 1));
        st32(prog + 2 * p + 1, (unsigned)(t + 1));
      }
      float hval = bf2f(stB[rb * RP + j0 + rj]);
      const unsigned short* yrow = stA + lm * RP;
      const unsigned short* hrow = stB + lm * RP;
      v4f az = {0, 0, 0, 0}, axr = {0, 0, 0, 0}, ahr = {0, 0, 0, 0}, ao = {0, 0, 0, 0};
      v8bf ahf[4];
#pragma unroll
      for (int kb = 0; kb < 4; kb++) {
        int k = wig * 128 + kb * 32 + lq * 8;
        v8bf ay = *(const v8bf*)(yrow + k);
        ahf[kb] = *(const v8bf*)(hrow + k);
        az = MFMA(ay, wzx1[kb], az);
        az = MFMA(ahf[kb], wzh[kb], az);
        axr = MFMA(ay, wrx1[kb], axr);
        ahr = MFMA(ahf[kb], wrh[kb], ahr);
      }
      if (OW && t > 0) {
#pragma unroll
        for (int kb = 0; kb < 4; kb++) ao = MFMA(ahf[kb], wo[kb], ao);  // out_{t-1}
      }
#pragma unroll
      for (int v = 0; v < 4; v++) {
        red[g][0][wig][lq * 4 + v][lm] = az[v];
        red[g][1][wig][lq * 4 + v][lm] = axr[v];
        red[g][2][wig][lq * 4 + v][lm] = ahr[v];
        if (OW) red[g][3][wig][lq * 4 + v][lm] = ao[v];
      }
      lgkm_barrier();  // B2
      float zs = 0, xrs = 0, hrs = 0, os = 0;
#pragma unroll
      for (int w = 0; w < 4; w++) {
        zs += red[g][0][w][rb][rj];
        xrs += red[g][1][w][rb][rj];
        hrs += red[g][2][w][rb][rj];
        if (OW) os += red[g][3][w][rb][rj];
      }
      float z = sigf(zs + bz);
      float r = sigf(xrs + hrs + br);
      store_val(u1d + (size_t)(t & 1) * 8192, oldwg, gtid, r * hval, (unsigned)(t + 1));
      post2(u1s + (t & 1) * 32, p, (unsigned)(t + 1), tid);  // B3 (no vm drain)
      // out-store after the post: off the exchange chain
      if (OW && t > 0) out[((size_t)rb * Sv + (t - 1)) * Ov + j0 + rj] = os + bo;
      poll1(u1s + (t & 1) * 32, (unsigned)(t + 1), tid);
      read_stage_tag(u1d + (size_t)(t & 1) * 8192, stC, tid, (unsigned)(t + 1));
      lgkm_barrier();  // B4
      const unsigned short* urow = stC + lm * RP;
      v4f ag = {0, 0, 0, 0};
#pragma unroll
      for (int kb = 0; kb < 4; kb++) {
        v8bf au = *(const v8bf*)(urow + wig * 128 + kb * 32 + lq * 8);
        ag = MFMA(au, wrh[kb], ag);
      }
#pragma unroll
      for (int v = 0; v < 4; v++) red[g][4][wig][lq * 4 + v][lm] = ag[v];
      lgkm_barrier();  // B5
      float gs = 0;
#pragma unroll
      for (int w = 0; w < 4; w++) gs += red[g][4][w][rb][rj];
      float gg = tanh_fast(xrs + gs + br);
      float hn = z * hval + (1.f - z) * gg;
      store_val(h1d + (size_t)((t + 1) & 3) * 8192, oldwg, gtid, hn, (unsigned)(t + 2));
      if (t == Sv - 1) out[(size_t)Bv * Sv * Ov + ((size_t)rb * 2 + 1) * Hv + j0 + rj] = hn;
      post2(h1s + ((t + 1) & 3) * 32, p, (unsigned)(t + 2), tid);  // B6 (no vm drain)
    }
    if (OW) {  // tail: out_{S-1} from y1_{S-1} = h1 tag S+1 at slot S&3
      poll1(h1s + (Sv & 3) * 32, (unsigned)(Sv + 1), tid);
      read_stage_tag(h1d + (size_t)(Sv & 3) * 8192, stB, tid, (unsigned)(Sv + 1));
      lgkm_barrier();
      const unsigned short* hrow = stB + lm * RP;
      v4f ao = {0, 0, 0, 0};
#pragma unroll
      for (int kb = 0; kb < 4; kb++) {
        v8bf ah = *(const v8bf*)(hrow + wig * 128 + kb * 32 + lq * 8);
        ao = MFMA(ah, wo[kb], ao);
      }
#pragma unroll
      for (int v = 0; v < 4; v++) red[g][3][wig][lq * 4 + v][lm] = ao[v];
      lgkm_barrier();
      float os = 0;
#pragma unroll
      for (int w = 0; w < 4; w++) os += red[g][3][w][rb][rj];
      out[((size_t)rb * Sv + (Sv - 1)) * Ov + j0 + rj] = os + bo;
    }
  }
}

extern "C" void kernel_launch(void* const* d_in, const int* in_sizes, int n_in,
                              void* d_out, int out_size, void* d_ws, size_t ws_size,
                              hipStream_t stream) {
  const float* x = (const float*)d_in[0];
  const float* hs = (const float*)d_in[1];
  const float* Wxz0 = (const float*)d_in[2];
  const float* Whz0 = (const float*)d_in[3];
  const float* bhz0 = (const float*)d_in[4];
  const float* Wxr0 = (const float*)d_in[5];
  const float* Whr0 = (const float*)d_in[6];
  const float* bhr0 = (const float*)d_in[7];
  const float* Wxz1 = (const float*)d_in[8];
  const float* Whz1 = (const float*)d_in[9];
  const float* bhz1 = (const float*)d_in[10];
  const float* Wxr1 = (const float*)d_in[11];
  const float* Whr1 = (const float*)d_in[12];
  const float* bhr1 = (const float*)d_in[13];
  const float* Why = (const float*)d_in[14];
  const float* by = (const float*)d_in[15];
  float* out = (float*)d_out;

  // y0-ring depth: largest pow2 (<=64, >=4) fitting ws (32KB tagged slots)
  int D = 64;
  while (D > 4 && 16384 + (size_t)(D + 8) * 32768 > ws_size) D >>= 1;

  // zero prog + claim + sentinels + ALL payload rings (stale tags must not match)
  size_t msz = 16384 + (size_t)(D + 8) * 32768;
  if (msz > ws_size) msz = ws_size;
  hipMemsetAsync(d_ws, 0, msz, stream);
  // 256 blocks x 512 threads, ~93KB LDS -> exactly 1 block/CU chip-wide;
  // workers claim themselves onto XCD 0, the rest exit.
  hipLaunchKernelGGL(gru_fused, dim3(256), dim3(512), 0, stream,
                     x, hs, Wxz0, Whz0, bhz0, Wxr0, Whr0, bhr0,
                     Wxz1, Whz1, bhz1, Wxr1, Whr1, bhr1, Why, by,
                     out, (char*)d_ws, D);
}